// Round 21
// baseline (135.400 us; speedup 1.0000x reference)
//
#include <hip/hip_runtime.h>
#include <hip/hip_bf16.h>

typedef __attribute__((ext_vector_type(8))) short s8b;
typedef __attribute__((ext_vector_type(4))) float f4;
typedef unsigned short u16;

union U8 { s8b v; unsigned long long u[2]; };

__device__ __forceinline__ u16 f2bf(float f) {
  union { float f; unsigned u; } x; x.f = f;
  unsigned r = x.u + 0x7fffu + ((x.u >> 16) & 1u);
  return (u16)(r >> 16);
}

__device__ __forceinline__ float exp2a(float x) {   // raw v_exp_f32 (2^x)
  float r;
  asm("v_exp_f32 %0, %1" : "=v"(r) : "v"(x));
  return r;
}

__device__ __forceinline__ void gload16(const void* g, void* l) {
  __builtin_amdgcn_global_load_lds(
      (const __attribute__((address_space(1))) void*)g,
      (__attribute__((address_space(3))) void*)l, 16, 0, 0);
}

// fused bf16 convert of x, w_attn, w_proj (2x float4 per thread)
__global__ void cvt3_kernel(const float* __restrict__ x, const float* __restrict__ wa,
                            const float* __restrict__ wp, u16* __restrict__ xb,
                            u16* __restrict__ wab, u16* __restrict__ wpb) {
  const int base = blockIdx.x * blockDim.x + threadIdx.x;
#pragma unroll
  for (int rep = 0; rep < 2; ++rep) {
    const int i = base + rep * 1572864;     // 6144*256
    const float4* src;
    ushort4* dst;
    int idx;
    if (i < 2097152) { src = (const float4*)x; dst = (ushort4*)xb; idx = i; }
    else if (i < 2883584) { src = (const float4*)wa; dst = (ushort4*)wab; idx = i - 2097152; }
    else { src = (const float4*)wp; dst = (ushort4*)wpb; idx = i - 2883584; }
    const float4 v = src[idx];
    ushort4 o;
    o.x = f2bf(v.x); o.y = f2bf(v.y); o.z = f2bf(v.z); o.w = f2bf(v.w);
    dst[idx] = o;
  }
}

#define BMT 128
#define BNT 128
#define BKT 64

// ---------------- single-buffer 128x128 GEMM, grid = tile count ------------
// m97 structure: 32KB LDS; per K-step compute -> barrier -> stage(next) ->
// barrier; cross-BLOCK overlap hides the stage drain (e2e-best for GEMM1).
// L2-affine walk: bm = xcd*8+(ib&7), bn = ib>>3.
template<int MODE>
__global__ __launch_bounds__(256, 2)
void gemm_sb(const u16* __restrict__ A, const u16* __restrict__ Bm,
             float* __restrict__ Cf,
             u16* __restrict__ qo, u16* __restrict__ ko, u16* __restrict__ vo,
             int N, int K) {
  __shared__ u16 lds[2][BMT * BKT];    // [A=0/B=1], 32 KB
  const int tid = threadIdx.x;
  const int lane = tid & 63;
  const int w = tid >> 6;
  const int wr = w >> 1, wc = w & 1;
  const int ric = lane >> 3;
  const int ssw = (lane & 7) ^ ric;

  const int d = blockIdx.x;
  const int xcd = d & 7, ib = d >> 3;
  const int bm = xcd * 8 + (ib & 7);
  const int bn = ib >> 3;
  const u16* Ab = A + (size_t)bm * BMT * K;
  const u16* Bb = Bm + (size_t)bn * BNT * K;

  auto stage = [&](int kt) {
    const int ko_ = kt * BKT;
#pragma unroll
    for (int c = 0; c < 4; ++c) {
      const int rch = w * 32 + c * 8;
      gload16(Ab + (size_t)(rch + ric) * K + ko_ + ssw * 8, &lds[0][rch * BKT]);
      gload16(Bb + (size_t)(rch + ric) * K + ko_ + ssw * 8, &lds[1][rch * BKT]);
    }
  };

  const int nk = K / BKT;
  f4 acc[4][4] = {};
  stage(0);
  __syncthreads();

  for (int kt = 0; kt < nk; ++kt) {
    const u16* At = &lds[0][0];
    const u16* Bt = &lds[1][0];
#pragma unroll
    for (int kk = 0; kk < 2; ++kk) {
      s8b a[4], b[4];
#pragma unroll
      for (int m = 0; m < 4; ++m) {
        const int row = wr * 64 + m * 16 + (lane & 15);
        a[m] = *(const s8b*)(At + row * BKT + ((((kk << 2) + (lane >> 4)) ^ (row & 7)) << 3));
      }
#pragma unroll
      for (int n = 0; n < 4; ++n) {
        const int row = wc * 64 + n * 16 + (lane & 15);
        b[n] = *(const s8b*)(Bt + row * BKT + ((((kk << 2) + (lane >> 4)) ^ (row & 7)) << 3));
      }
#pragma unroll
      for (int m = 0; m < 4; ++m)
#pragma unroll
        for (int n = 0; n < 4; ++n)
          acc[m][n] = __builtin_amdgcn_mfma_f32_16x16x32_bf16(a[m], b[n], acc[m][n], 0, 0, 0);
    }
    __syncthreads();
    if (kt + 1 < nk) {
      stage(kt + 1);
      __syncthreads();
    }
  }

  if (MODE == 0) {
#pragma unroll
    for (int n = 0; n < 4; ++n) {
      const int f = bn * BNT + wc * 64 + n * 16 + (lane & 15);
      const int which = f >> 10;
      const int rem = f & 1023;
      const int h = rem >> 6, dd = rem & 63;
      if (which == 2) {
#pragma unroll
        for (int m = 0; m < 4; ++m) {
          const int i0 = bm * BMT + wr * 64 + m * 16 + (lane >> 4) * 4;
          const int bb = i0 >> 11, t0 = i0 & 2047;
          ushort4 pk;
          pk.x = f2bf(acc[m][n][0]);
          pk.y = f2bf(acc[m][n][1]);
          pk.z = f2bf(acc[m][n][2]);
          pk.w = f2bf(acc[m][n][3]);
          *(ushort4*)(&vo[((size_t)((bb << 4) + h) * 64 + dd) * 2048 + t0]) = pk;
        }
      } else {
        u16* dst = which == 0 ? qo : ko;
        // Q pre-scaled by (1/sqrt(64)) * log2(e) for exp2-domain softmax
        const float sc = which == 0 ? 0.18033688f : 1.0f;
#pragma unroll
        for (int m = 0; m < 4; ++m) {
#pragma unroll
          for (int j = 0; j < 4; ++j) {
            const int i = bm * BMT + wr * 64 + m * 16 + (lane >> 4) * 4 + j;
            const int bb = i >> 11, tt = i & 2047;
            dst[((size_t)((bb << 4) + h) * 2048 + tt) * 64 + dd] = f2bf(acc[m][n][j] * sc);
          }
        }
      }
    }
  } else {
#pragma unroll
    for (int m = 0; m < 4; ++m) {
#pragma unroll
      for (int j = 0; j < 4; ++j) {
        const int i = bm * BMT + wr * 64 + m * 16 + (lane >> 4) * 4 + j;
#pragma unroll
        for (int n = 0; n < 4; ++n) {
          const int f = bn * BNT + wc * 64 + n * 16 + (lane & 15);
          Cf[(size_t)i * N + f] = acc[m][n][j];
        }
      }
    }
  }
}

// ---------------- 2-phase 128x128 GEMM, persistent, 2-step unrolled --------
// (used for GEMM2 where grid=512 caps residency at 2/CU anyway)
template<int MODE, int TILES>
__global__ __launch_bounds__(256, 2)
void gemm_bt(const u16* __restrict__ A, const u16* __restrict__ Bm,
             float* __restrict__ Cf,
             u16* __restrict__ qo, u16* __restrict__ ko, u16* __restrict__ vo,
             int N, int K, int GX) {
  __shared__ u16 lds[2][2][BMT * BKT];
  const int tid = threadIdx.x;
  const int lane = tid & 63;
  const int w = tid >> 6;
  const int wr = w >> 1, wc = w & 1;
  const int ric = lane >> 3;
  const int ssw = (lane & 7) ^ ric;

  auto tile_ptrs = [&](int t, const u16*& Ab, const u16*& Bb, int& bm, int& bn) {
    const int d = blockIdx.x + t * gridDim.x;
    const int xcd = d & 7, ib = d >> 3;
    bm = xcd * 8 + (ib & 7);
    bn = ib >> 3;
    Ab = A + (size_t)bm * BMT * K;
    Bb = Bm + (size_t)bn * BNT * K;
  };

  const int nk = K / BKT;          // even (16)
  const u16 *Ab, *Bb, *AbN, *BbN;
  int bm, bn, bmN, bnN;
  tile_ptrs(0, Ab, Bb, bm, bn);

  {
#pragma unroll
    for (int c = 0; c < 4; ++c) {
      const int rch = w * 32 + c * 8;
      gload16(Ab + (size_t)(rch + ric) * K + ssw * 8, &lds[0][0][rch * BKT]);
      gload16(Bb + (size_t)(rch + ric) * K + ssw * 8, &lds[0][1][rch * BKT]);
    }
  }
  __syncthreads();

  for (int t = 0; t < TILES; ++t) {
    if (t + 1 < TILES) tile_ptrs(t + 1, AbN, BbN, bmN, bnN);
    f4 acc[4][4] = {};

    for (int kt = 0; kt < nk; kt += 2) {
#pragma unroll
      for (int h = 0; h < 2; ++h) {
        const int ktg = kt + h;
        {
          const u16* sA;
          const u16* sB;
          int ko_;
          bool do_stage = true;
          if (ktg + 1 < nk) { sA = Ab; sB = Bb; ko_ = (ktg + 1) * BKT; }
          else if (t + 1 < TILES) { sA = AbN; sB = BbN; ko_ = 0; }
          else do_stage = false;
          if (do_stage) {
#pragma unroll
            for (int c = 0; c < 4; ++c) {
              const int rch = w * 32 + c * 8;
              gload16(sA + (size_t)(rch + ric) * K + ko_ + ssw * 8, &lds[h ^ 1][0][rch * BKT]);
              gload16(sB + (size_t)(rch + ric) * K + ko_ + ssw * 8, &lds[h ^ 1][1][rch * BKT]);
            }
          }
        }
        const u16* At = &lds[h][0][0];
        const u16* Bt = &lds[h][1][0];
#pragma unroll
        for (int kk = 0; kk < 2; ++kk) {
          s8b a[4], b[4];
#pragma unroll
          for (int m = 0; m < 4; ++m) {
            const int row = wr * 64 + m * 16 + (lane & 15);
            a[m] = *(const s8b*)(At + row * BKT + ((((kk << 2) + (lane >> 4)) ^ (row & 7)) << 3));
          }
#pragma unroll
          for (int n = 0; n < 4; ++n) {
            const int row = wc * 64 + n * 16 + (lane & 15);
            b[n] = *(const s8b*)(Bt + row * BKT + ((((kk << 2) + (lane >> 4)) ^ (row & 7)) << 3));
          }
#pragma unroll
          for (int m = 0; m < 4; ++m)
#pragma unroll
            for (int n = 0; n < 4; ++n)
              acc[m][n] = __builtin_amdgcn_mfma_f32_16x16x32_bf16(a[m], b[n], acc[m][n], 0, 0, 0);
        }
        __syncthreads();
      }
    }

    if (MODE == 0) {
#pragma unroll
      for (int n = 0; n < 4; ++n) {
        const int f = bn * BNT + wc * 64 + n * 16 + (lane & 15);
        const int which = f >> 10;
        const int rem = f & 1023;
        const int h = rem >> 6, dd = rem & 63;
        if (which == 2) {
#pragma unroll
          for (int m = 0; m < 4; ++m) {
            const int i0 = bm * BMT + wr * 64 + m * 16 + (lane >> 4) * 4;
            const int bb = i0 >> 11, t0 = i0 & 2047;
            ushort4 pk;
            pk.x = f2bf(acc[m][n][0]);
            pk.y = f2bf(acc[m][n][1]);
            pk.z = f2bf(acc[m][n][2]);
            pk.w = f2bf(acc[m][n][3]);
            *(ushort4*)(&vo[((size_t)((bb << 4) + h) * 64 + dd) * 2048 + t0]) = pk;
          }
        } else {
          u16* dst = which == 0 ? qo : ko;
          const float sc = which == 0 ? 0.18033688f : 1.0f;
#pragma unroll
          for (int m = 0; m < 4; ++m) {
#pragma unroll
            for (int j = 0; j < 4; ++j) {
              const int i = bm * BMT + wr * 64 + m * 16 + (lane >> 4) * 4 + j;
              const int bb = i >> 11, tt = i & 2047;
              dst[((size_t)((bb << 4) + h) * 2048 + tt) * 64 + dd] = f2bf(acc[m][n][j] * sc);
            }
          }
        }
      }
    } else {
#pragma unroll
      for (int m = 0; m < 4; ++m) {
#pragma unroll
        for (int j = 0; j < 4; ++j) {
          const int i = bm * BMT + wr * 64 + m * 16 + (lane >> 4) * 4 + j;
#pragma unroll
          for (int n = 0; n < 4; ++n) {
            const int f = bn * BNT + wc * 64 + n * 16 + (lane & 15);
            Cf[(size_t)i * N + f] = acc[m][n][j];
          }
        }
      }
    }

    Ab = AbN; Bb = BbN; bm = bmN; bn = bnN;
  }
}

// ---------------- Flash attention v10: masked-wave skip on diagonal tail ---
// As v9 (single-buffer K/V, 24KB LDS, fixed-max exp2, MFMA rowsum), plus:
// on the LAST kv tile of each q-tile, waves w<2 cover q-rows entirely below
// kv_start (q < (2qi+1)*64) -> fully masked -> skip their QK/softmax/PV
// (contribution is exactly 0). Barriers preserved for all waves.
__global__ __launch_bounds__(256, 3)
void attn_kernel(const u16* __restrict__ q, const u16* __restrict__ k,
                 const u16* __restrict__ vt, u16* __restrict__ ao) {
  __shared__ u16 Kl[64 * 64];
  __shared__ u16 VTl[64 * 64];
  __shared__ u16 Pl[4][16 * 64];      // per-wave, time-shared between groups
  const int tid = threadIdx.x, lane = tid & 63, w = tid >> 6;
  const int dd = blockIdx.x;
  const int xcd = dd & 7, ib = dd >> 3;
  const int bh = xcd * 8 + (ib & 7);
  const int j4 = ib >> 3;                  // 0..15
  const int s4 = j4 >> 2, r4 = j4 & 3;
  const int qi = (s4 == 0) ? 15 - r4 : (s4 == 1) ? 8 + r4 : (s4 == 2) ? 7 - r4 : r4;
  const int b = bh >> 4, h16 = bh & 15;
  const size_t hb = (size_t)bh * 2048 * 64;
  const int qlo = lane & 15, hi = lane >> 4;
  const int r0 = tid >> 3, sl = tid & 7;
  u16* pw = &Pl[w][0];

  const s8b ones = {16256, 16256, 16256, 16256, 16256, 16256, 16256, 16256};

  const u16* kp = k + hb + (size_t)r0 * 64 + sl * 8;
  const u16* vp = vt + hb + (size_t)r0 * 2048 + sl * 8;
  s8b kr[2], vr[2];
  auto load_regs = [&]() {
    kr[0] = *(const s8b*)kp;
    kr[1] = *(const s8b*)(kp + 32 * 64);
    vr[0] = *(const s8b*)vp;
    vr[1] = *(const s8b*)(vp + 32 * 2048);
    kp += 64 * 64;
    vp += 64;
  };
  auto write_lds = [&]() {
#pragma unroll
    for (int c0 = 0; c0 < 2; ++c0) {
      const int r = r0 + c0 * 32;
      const int off = r * 64 + ((sl ^ (r & 7) ^ (r >> 3)) << 3);
      *(s8b*)(&Kl[off]) = kr[c0];
      *(s8b*)(&VTl[off]) = vr[c0];
    }
  };

  auto softpack = [&](f4 (&s)[4], U8 (&pf)[2]) {
#pragma unroll
    for (int n = 0; n < 4; ++n)
#pragma unroll
      for (int j = 0; j < 4; ++j) s[n][j] = exp2a(s[n][j]);
#pragma unroll
    for (int n = 0; n < 4; ++n) {
      __hip_bfloat162 h0 = __float22bfloat162_rn(make_float2(s[n][0], s[n][1]));
      __hip_bfloat162 h1 = __float22bfloat162_rn(make_float2(s[n][2], s[n][3]));
      unsigned lo, hi2;
      __builtin_memcpy(&lo, &h0, 4);
      __builtin_memcpy(&hi2, &h1, 4);
      const unsigned long long w64 =
          (unsigned long long)lo | ((unsigned long long)hi2 << 32);
      const int cw = ((n << 2) + hi) ^ qlo;
      *(unsigned long long*)(pw + (qlo << 6) + (cw << 2)) = w64;
    }
#pragma unroll
    for (int kk = 0; kk < 2; ++kk) {
      const int ca = ((kk << 3) + (hi << 1)) ^ qlo;
      pf[kk].u[0] = *(const unsigned long long*)(pw + (qlo << 6) + (ca << 2));
      pf[kk].u[1] = *(const unsigned long long*)(pw + (qlo << 6) + ((ca ^ 1) << 2));
    }
  };

  const int nkt = 2 * qi + 2;              // kv tiles of 64
  s8b qf[2][2];
#pragma unroll
  for (int g = 0; g < 2; ++g) {
    const u16* qp = q + hb + (size_t)(qi * 128 + w * 32 + g * 16 + qlo) * 64 + hi * 8;
    qf[g][0] = *(const s8b*)qp;
    qf[g][1] = *(const s8b*)(qp + 32);
  }
  f4 acc0[5] = {}, acc1[5] = {};

  load_regs();                             // tile 0
  write_lds();
  __syncthreads();

  for (int kt = 0; kt < nkt; ++kt) {
    const bool pf_next = (kt + 1 < nkt);
    if (pf_next) load_regs();              // global loads fly under compute

    // last kv tile: waves w<2 have q-rows entirely below kv_start -> skip
    const bool active = pf_next || (w >= 2);

    if (active) {
      f4 s0[4], s1[4];
#pragma unroll
      for (int n = 0; n < 4; ++n) {
        s0[n] = (f4){-64.f, -64.f, -64.f, -64.f};
        s1[n] = (f4){-64.f, -64.f, -64.f, -64.f};
      }
      __builtin_amdgcn_s_setprio(1);
#pragma unroll
      for (int n = 0; n < 4; ++n) {
        const int row = n * 16 + qlo;
        const int swz = (row & 7) ^ (row >> 3);
#pragma unroll
        for (int kk = 0; kk < 2; ++kk) {
          const s8b kf = *(const s8b*)(&Kl[row * 64 + ((((kk << 2) + hi) ^ swz) << 3)]);
          s0[n] = __builtin_amdgcn_mfma_f32_16x16x32_bf16(kf, qf[0][kk], s0[n], 0, 0, 0);
          s1[n] = __builtin_amdgcn_mfma_f32_16x16x32_bf16(kf, qf[1][kk], s1[n], 0, 0, 0);
        }
      }
      __builtin_amdgcn_s_setprio(0);

      const int dmb = (2 * qi - kt) * 64;
      if (dmb < 64) {
        const int thr0 = w * 32 + qlo + dmb;
        const int thr1 = thr0 + 16;
#pragma unroll
        for (int n = 0; n < 4; ++n)
#pragma unroll
          for (int j = 0; j < 4; ++j) {
            const int kidx = n * 16 + hi * 4 + j;
            if (kidx > thr0) s0[n][j] = -1e30f;
            if (kidx > thr1) s1[n][j] = -1e30f;
          }
      }

      U8 pf0[2], pf1[2];
      softpack(s0, pf0);
      softpack(s1, pf1);

      __builtin_amdgcn_s_setprio(1);
#pragma unroll
      for (int dn = 0; dn < 4; ++dn) {
        const int vrow = dn * 16 + qlo;
        const int vswz = (vrow & 7) ^ (vrow >> 3);
#pragma unroll
        for (int kk = 0; kk < 2; ++kk) {
          const s8b vf = *(const s8b*)(&VTl[vrow * 64 + ((((kk << 2) + hi) ^ vswz) << 3)]);
          acc0[dn] = __builtin_amdgcn_mfma_f32_16x16x32_bf16(pf0[kk].v, vf, acc0[dn], 0, 0, 0);
          acc1[dn] = __builtin_amdgcn_mfma_f32_16x16x32_bf16(pf1[kk].v, vf, acc1[dn], 0, 0, 0);
        }
      }
#pragma unroll
      for (int kk = 0; kk < 2; ++kk) {
        acc0[4] = __builtin_amdgcn_mfma_f32_16x16x32_bf16(pf0[kk].v, ones, acc0[4], 0, 0, 0);
        acc1[4] = __builtin_amdgcn_mfma_f32_16x16x32_bf16(pf1[kk].v, ones, acc1[4], 0, 0, 0);
      }
      __builtin_amdgcn_s_setprio(0);
    }

    __syncthreads();
    if (pf_next) {
      write_lds();
      __syncthreads();
    }
  }

#pragma unroll
  for (int g = 0; g < 2; ++g) {
    const f4* accg = g ? acc1 : acc0;
#pragma unroll
    for (int j = 0; j < 4; ++j) {
      const float rl = 1.0f / accg[4][j];
      const int t = qi * 128 + w * 32 + g * 16 + hi * 4 + j;
#pragma unroll
      for (int dn = 0; dn < 4; ++dn) {
        const int dcol = dn * 16 + qlo;
        ao[((size_t)(b * 2048 + t)) * 1024 + h16 * 64 + dcol] = f2bf(accg[dn][j] * rl);
      }
    }
  }
}

extern "C" void kernel_launch(void* const* d_in, const int* in_sizes, int n_in,
                              void* d_out, int out_size, void* d_ws, size_t ws_size,
                              hipStream_t stream) {
  const float* x = (const float*)d_in[0];
  const float* w_attn = (const float*)d_in[1];
  const float* w_proj = (const float*)d_in[2];
  float* out = (float*)d_out;
  char* ws = (char*)d_ws;

  u16* xb  = (u16*)(ws);
  u16* wab = (u16*)(ws + (16u << 20));
  u16* wpb = (u16*)(ws + (22u << 20));
  u16* qb  = (u16*)(ws + (24u << 20));
  u16* kb  = (u16*)(ws + (40u << 20));
  u16* vb  = (u16*)(ws + (56u << 20));   // V^T [B,H,D,T]
  u16* ao  = xb;  // alias: xb dead after GEMM1

  cvt3_kernel<<<6144, 256, 0, stream>>>(x, w_attn, w_proj, xb, wab, wpb);

  // GEMM1: M=8192, N=3072, K=1024 -> 1536 blocks, single-buffer m97 structure
  gemm_sb<0><<<1536, 256, 0, stream>>>(xb, wab, nullptr, qb, kb, vb,
                                       3072, 1024);
  // attn: 1024 blocks, 24KB LDS single-buffer, masked-wave skip
  attn_kernel<<<1024, 256, 0, stream>>>(qb, kb, vb, ao);
  // GEMM2: M=8192, N=1024, K=1024 -> 512 blocks x 1 tile (double-buffered)
  gemm_bt<1, 1><<<512, 256, 0, stream>>>(ao, wpb, out, nullptr, nullptr, nullptr,
                                         1024, 1024, 8);
}

// Round 22
// 134.951 us; speedup vs baseline: 1.0033x; 1.0033x over previous
//
#include <hip/hip_runtime.h>
#include <hip/hip_bf16.h>

typedef __attribute__((ext_vector_type(8))) short s8b;
typedef __attribute__((ext_vector_type(4))) float f4;
typedef unsigned short u16;

union U8 { s8b v; unsigned long long u[2]; };

__device__ __forceinline__ u16 f2bf(float f) {
  union { float f; unsigned u; } x; x.f = f;
  unsigned r = x.u + 0x7fffu + ((x.u >> 16) & 1u);
  return (u16)(r >> 16);
}

__device__ __forceinline__ float exp2a(float x) {   // raw v_exp_f32 (2^x)
  float r;
  asm("v_exp_f32 %0, %1" : "=v"(r) : "v"(x));
  return r;
}

__device__ __forceinline__ void gload16(const void* g, void* l) {
  __builtin_amdgcn_global_load_lds(
      (const __attribute__((address_space(1))) void*)g,
      (__attribute__((address_space(3))) void*)l, 16, 0, 0);
}

// fused bf16 convert of x, w_attn, w_proj (2x float4 per thread)
__global__ void cvt3_kernel(const float* __restrict__ x, const float* __restrict__ wa,
                            const float* __restrict__ wp, u16* __restrict__ xb,
                            u16* __restrict__ wab, u16* __restrict__ wpb) {
  const int base = blockIdx.x * blockDim.x + threadIdx.x;
#pragma unroll
  for (int rep = 0; rep < 2; ++rep) {
    const int i = base + rep * 1572864;     // 6144*256
    const float4* src;
    ushort4* dst;
    int idx;
    if (i < 2097152) { src = (const float4*)x; dst = (ushort4*)xb; idx = i; }
    else if (i < 2883584) { src = (const float4*)wa; dst = (ushort4*)wab; idx = i - 2097152; }
    else { src = (const float4*)wp; dst = (ushort4*)wpb; idx = i - 2883584; }
    const float4 v = src[idx];
    ushort4 o;
    o.x = f2bf(v.x); o.y = f2bf(v.y); o.z = f2bf(v.z); o.w = f2bf(v.w);
    dst[idx] = o;
  }
}

#define BMT 128
#define BNT 128
#define BKT 64

// ---------------- single-buffer 128x128 GEMM, grid = tile count ------------
// m97 structure: 32KB LDS; per K-step compute -> barrier -> stage(next) ->
// barrier; cross-BLOCK overlap hides the stage drain (e2e-best for GEMM1).
// L2-affine walk: bm = xcd*8+(ib&7), bn = ib>>3.
template<int MODE>
__global__ __launch_bounds__(256, 4)
void gemm_sb(const u16* __restrict__ A, const u16* __restrict__ Bm,
             float* __restrict__ Cf,
             u16* __restrict__ qo, u16* __restrict__ ko, u16* __restrict__ vo,
             int N, int K) {
  __shared__ u16 lds[2][BMT * BKT];    // [A=0/B=1], 32 KB
  const int tid = threadIdx.x;
  const int lane = tid & 63;
  const int w = tid >> 6;
  const int wr = w >> 1, wc = w & 1;
  const int ric = lane >> 3;
  const int ssw = (lane & 7) ^ ric;

  const int d = blockIdx.x;
  const int xcd = d & 7, ib = d >> 3;
  const int bm = xcd * 8 + (ib & 7);
  const int bn = ib >> 3;
  const u16* Ab = A + (size_t)bm * BMT * K;
  const u16* Bb = Bm + (size_t)bn * BNT * K;

  auto stage = [&](int kt) {
    const int ko_ = kt * BKT;
#pragma unroll
    for (int c = 0; c < 4; ++c) {
      const int rch = w * 32 + c * 8;
      gload16(Ab + (size_t)(rch + ric) * K + ko_ + ssw * 8, &lds[0][rch * BKT]);
      gload16(Bb + (size_t)(rch + ric) * K + ko_ + ssw * 8, &lds[1][rch * BKT]);
    }
  };

  const int nk = K / BKT;
  f4 acc[4][4] = {};
  stage(0);
  __syncthreads();

  for (int kt = 0; kt < nk; ++kt) {
    const u16* At = &lds[0][0];
    const u16* Bt = &lds[1][0];
#pragma unroll
    for (int kk = 0; kk < 2; ++kk) {
      s8b a[4], b[4];
#pragma unroll
      for (int m = 0; m < 4; ++m) {
        const int row = wr * 64 + m * 16 + (lane & 15);
        a[m] = *(const s8b*)(At + row * BKT + ((((kk << 2) + (lane >> 4)) ^ (row & 7)) << 3));
      }
#pragma unroll
      for (int n = 0; n < 4; ++n) {
        const int row = wc * 64 + n * 16 + (lane & 15);
        b[n] = *(const s8b*)(Bt + row * BKT + ((((kk << 2) + (lane >> 4)) ^ (row & 7)) << 3));
      }
#pragma unroll
      for (int m = 0; m < 4; ++m)
#pragma unroll
        for (int n = 0; n < 4; ++n)
          acc[m][n] = __builtin_amdgcn_mfma_f32_16x16x32_bf16(a[m], b[n], acc[m][n], 0, 0, 0);
    }
    __syncthreads();
    if (kt + 1 < nk) {
      stage(kt + 1);
      __syncthreads();
    }
  }

  if (MODE == 0) {
#pragma unroll
    for (int n = 0; n < 4; ++n) {
      const int f = bn * BNT + wc * 64 + n * 16 + (lane & 15);
      const int which = f >> 10;
      const int rem = f & 1023;
      const int h = rem >> 6, dd = rem & 63;
      if (which == 2) {
#pragma unroll
        for (int m = 0; m < 4; ++m) {
          const int i0 = bm * BMT + wr * 64 + m * 16 + (lane >> 4) * 4;
          const int bb = i0 >> 11, t0 = i0 & 2047;
          ushort4 pk;
          pk.x = f2bf(acc[m][n][0]);
          pk.y = f2bf(acc[m][n][1]);
          pk.z = f2bf(acc[m][n][2]);
          pk.w = f2bf(acc[m][n][3]);
          *(ushort4*)(&vo[((size_t)((bb << 4) + h) * 64 + dd) * 2048 + t0]) = pk;
        }
      } else {
        u16* dst = which == 0 ? qo : ko;
        // Q pre-scaled by (1/sqrt(64)) * log2(e) for exp2-domain softmax
        const float sc = which == 0 ? 0.18033688f : 1.0f;
#pragma unroll
        for (int m = 0; m < 4; ++m) {
#pragma unroll
          for (int j = 0; j < 4; ++j) {
            const int i = bm * BMT + wr * 64 + m * 16 + (lane >> 4) * 4 + j;
            const int bb = i >> 11, tt = i & 2047;
            dst[((size_t)((bb << 4) + h) * 2048 + tt) * 64 + dd] = f2bf(acc[m][n][j] * sc);
          }
        }
      }
    }
  } else {
#pragma unroll
    for (int m = 0; m < 4; ++m) {
#pragma unroll
      for (int j = 0; j < 4; ++j) {
        const int i = bm * BMT + wr * 64 + m * 16 + (lane >> 4) * 4 + j;
#pragma unroll
        for (int n = 0; n < 4; ++n) {
          const int f = bn * BNT + wc * 64 + n * 16 + (lane & 15);
          Cf[(size_t)i * N + f] = acc[m][n][j];
        }
      }
    }
  }
}

// ---------------- 2-phase 128x128 GEMM, persistent, 2-step unrolled --------
// (used for GEMM2 where grid=512 caps residency at 2/CU anyway)
template<int MODE, int TILES>
__global__ __launch_bounds__(256, 2)
void gemm_bt(const u16* __restrict__ A, const u16* __restrict__ Bm,
             float* __restrict__ Cf,
             u16* __restrict__ qo, u16* __restrict__ ko, u16* __restrict__ vo,
             int N, int K, int GX) {
  __shared__ u16 lds[2][2][BMT * BKT];
  const int tid = threadIdx.x;
  const int lane = tid & 63;
  const int w = tid >> 6;
  const int wr = w >> 1, wc = w & 1;
  const int ric = lane >> 3;
  const int ssw = (lane & 7) ^ ric;

  auto tile_ptrs = [&](int t, const u16*& Ab, const u16*& Bb, int& bm, int& bn) {
    const int d = blockIdx.x + t * gridDim.x;
    const int xcd = d & 7, ib = d >> 3;
    bm = xcd * 8 + (ib & 7);
    bn = ib >> 3;
    Ab = A + (size_t)bm * BMT * K;
    Bb = Bm + (size_t)bn * BNT * K;
  };

  const int nk = K / BKT;          // even (16)
  const u16 *Ab, *Bb, *AbN, *BbN;
  int bm, bn, bmN, bnN;
  tile_ptrs(0, Ab, Bb, bm, bn);

  {
#pragma unroll
    for (int c = 0; c < 4; ++c) {
      const int rch = w * 32 + c * 8;
      gload16(Ab + (size_t)(rch + ric) * K + ssw * 8, &lds[0][0][rch * BKT]);
      gload16(Bb + (size_t)(rch + ric) * K + ssw * 8, &lds[0][1][rch * BKT]);
    }
  }
  __syncthreads();

  for (int t = 0; t < TILES; ++t) {
    if (t + 1 < TILES) tile_ptrs(t + 1, AbN, BbN, bmN, bnN);
    f4 acc[4][4] = {};

    for (int kt = 0; kt < nk; kt += 2) {
#pragma unroll
      for (int h = 0; h < 2; ++h) {
        const int ktg = kt + h;
        {
          const u16* sA;
          const u16* sB;
          int ko_;
          bool do_stage = true;
          if (ktg + 1 < nk) { sA = Ab; sB = Bb; ko_ = (ktg + 1) * BKT; }
          else if (t + 1 < TILES) { sA = AbN; sB = BbN; ko_ = 0; }
          else do_stage = false;
          if (do_stage) {
#pragma unroll
            for (int c = 0; c < 4; ++c) {
              const int rch = w * 32 + c * 8;
              gload16(sA + (size_t)(rch + ric) * K + ko_ + ssw * 8, &lds[h ^ 1][0][rch * BKT]);
              gload16(sB + (size_t)(rch + ric) * K + ko_ + ssw * 8, &lds[h ^ 1][1][rch * BKT]);
            }
          }
        }
        const u16* At = &lds[h][0][0];
        const u16* Bt = &lds[h][1][0];
#pragma unroll
        for (int kk = 0; kk < 2; ++kk) {
          s8b a[4], b[4];
#pragma unroll
          for (int m = 0; m < 4; ++m) {
            const int row = wr * 64 + m * 16 + (lane & 15);
            a[m] = *(const s8b*)(At + row * BKT + ((((kk << 2) + (lane >> 4)) ^ (row & 7)) << 3));
          }
#pragma unroll
          for (int n = 0; n < 4; ++n) {
            const int row = wc * 64 + n * 16 + (lane & 15);
            b[n] = *(const s8b*)(Bt + row * BKT + ((((kk << 2) + (lane >> 4)) ^ (row & 7)) << 3));
          }
#pragma unroll
          for (int m = 0; m < 4; ++m)
#pragma unroll
            for (int n = 0; n < 4; ++n)
              acc[m][n] = __builtin_amdgcn_mfma_f32_16x16x32_bf16(a[m], b[n], acc[m][n], 0, 0, 0);
        }
        __syncthreads();
      }
    }

    if (MODE == 0) {
#pragma unroll
      for (int n = 0; n < 4; ++n) {
        const int f = bn * BNT + wc * 64 + n * 16 + (lane & 15);
        const int which = f >> 10;
        const int rem = f & 1023;
        const int h = rem >> 6, dd = rem & 63;
        if (which == 2) {
#pragma unroll
          for (int m = 0; m < 4; ++m) {
            const int i0 = bm * BMT + wr * 64 + m * 16 + (lane >> 4) * 4;
            const int bb = i0 >> 11, t0 = i0 & 2047;
            ushort4 pk;
            pk.x = f2bf(acc[m][n][0]);
            pk.y = f2bf(acc[m][n][1]);
            pk.z = f2bf(acc[m][n][2]);
            pk.w = f2bf(acc[m][n][3]);
            *(ushort4*)(&vo[((size_t)((bb << 4) + h) * 64 + dd) * 2048 + t0]) = pk;
          }
        } else {
          u16* dst = which == 0 ? qo : ko;
          const float sc = which == 0 ? 0.18033688f : 1.0f;
#pragma unroll
          for (int m = 0; m < 4; ++m) {
#pragma unroll
            for (int j = 0; j < 4; ++j) {
              const int i = bm * BMT + wr * 64 + m * 16 + (lane >> 4) * 4 + j;
              const int bb = i >> 11, tt = i & 2047;
              dst[((size_t)((bb << 4) + h) * 2048 + tt) * 64 + dd] = f2bf(acc[m][n][j] * sc);
            }
          }
        }
      }
    } else {
#pragma unroll
      for (int m = 0; m < 4; ++m) {
#pragma unroll
        for (int j = 0; j < 4; ++j) {
          const int i = bm * BMT + wr * 64 + m * 16 + (lane >> 4) * 4 + j;
#pragma unroll
          for (int n = 0; n < 4; ++n) {
            const int f = bn * BNT + wc * 64 + n * 16 + (lane & 15);
            Cf[(size_t)i * N + f] = acc[m][n][j];
          }
        }
      }
    }

    Ab = AbN; Bb = BbN; bm = bmN; bn = bnN;
  }
}

// ---------------- Flash attention v9: single-buffer K/V, 24KB LDS ---------
// Grid 1024 = 4 blocks/CU resident. T14 async split: next tile's global
// loads issue before compute; LDS write after a barrier. Fixed-max exp2
// softmax (bias -64 folded into MFMA C-init); acc[4] = row-sum via B=ones.
// qi in mod-4 balanced classes (each CU's resident set sums to ~equal work).
__global__ __launch_bounds__(256, 3)
void attn_kernel(const u16* __restrict__ q, const u16* __restrict__ k,
                 const u16* __restrict__ vt, u16* __restrict__ ao) {
  __shared__ u16 Kl[64 * 64];
  __shared__ u16 VTl[64 * 64];
  __shared__ u16 Pl[4][16 * 64];      // per-wave, time-shared between groups
  const int tid = threadIdx.x, lane = tid & 63, w = tid >> 6;
  const int dd = blockIdx.x;
  const int xcd = dd & 7, ib = dd >> 3;
  const int bh = xcd * 8 + (ib & 7);
  const int j4 = ib >> 3;                  // 0..15
  const int s4 = j4 >> 2, r4 = j4 & 3;
  const int qi = (s4 == 0) ? 15 - r4 : (s4 == 1) ? 8 + r4 : (s4 == 2) ? 7 - r4 : r4;
  const int b = bh >> 4, h16 = bh & 15;
  const size_t hb = (size_t)bh * 2048 * 64;
  const int qlo = lane & 15, hi = lane >> 4;
  const int r0 = tid >> 3, sl = tid & 7;
  u16* pw = &Pl[w][0];

  const s8b ones = {16256, 16256, 16256, 16256, 16256, 16256, 16256, 16256};

  const u16* kp = k + hb + (size_t)r0 * 64 + sl * 8;
  const u16* vp = vt + hb + (size_t)r0 * 2048 + sl * 8;
  s8b kr[2], vr[2];
  auto load_regs = [&]() {
    kr[0] = *(const s8b*)kp;
    kr[1] = *(const s8b*)(kp + 32 * 64);
    vr[0] = *(const s8b*)vp;
    vr[1] = *(const s8b*)(vp + 32 * 2048);
    kp += 64 * 64;
    vp += 64;
  };
  auto write_lds = [&]() {
#pragma unroll
    for (int c0 = 0; c0 < 2; ++c0) {
      const int r = r0 + c0 * 32;
      const int off = r * 64 + ((sl ^ (r & 7) ^ (r >> 3)) << 3);
      *(s8b*)(&Kl[off]) = kr[c0];
      *(s8b*)(&VTl[off]) = vr[c0];
    }
  };

  auto softpack = [&](f4 (&s)[4], U8 (&pf)[2]) {
#pragma unroll
    for (int n = 0; n < 4; ++n)
#pragma unroll
      for (int j = 0; j < 4; ++j) s[n][j] = exp2a(s[n][j]);
#pragma unroll
    for (int n = 0; n < 4; ++n) {
      __hip_bfloat162 h0 = __float22bfloat162_rn(make_float2(s[n][0], s[n][1]));
      __hip_bfloat162 h1 = __float22bfloat162_rn(make_float2(s[n][2], s[n][3]));
      unsigned lo, hi2;
      __builtin_memcpy(&lo, &h0, 4);
      __builtin_memcpy(&hi2, &h1, 4);
      const unsigned long long w64 =
          (unsigned long long)lo | ((unsigned long long)hi2 << 32);
      const int cw = ((n << 2) + hi) ^ qlo;
      *(unsigned long long*)(pw + (qlo << 6) + (cw << 2)) = w64;
    }
#pragma unroll
    for (int kk = 0; kk < 2; ++kk) {
      const int ca = ((kk << 3) + (hi << 1)) ^ qlo;
      pf[kk].u[0] = *(const unsigned long long*)(pw + (qlo << 6) + (ca << 2));
      pf[kk].u[1] = *(const unsigned long long*)(pw + (qlo << 6) + ((ca ^ 1) << 2));
    }
  };

  const int nkt = 2 * qi + 2;              // kv tiles of 64
  s8b qf[2][2];
#pragma unroll
  for (int g = 0; g < 2; ++g) {
    const u16* qp = q + hb + (size_t)(qi * 128 + w * 32 + g * 16 + qlo) * 64 + hi * 8;
    qf[g][0] = *(const s8b*)qp;
    qf[g][1] = *(const s8b*)(qp + 32);
  }
  f4 acc0[5] = {}, acc1[5] = {};

  load_regs();                             // tile 0
  write_lds();
  __syncthreads();

  for (int kt = 0; kt < nkt; ++kt) {
    const bool pf_next = (kt + 1 < nkt);
    if (pf_next) load_regs();              // global loads fly under compute

    f4 s0[4], s1[4];
#pragma unroll
    for (int n = 0; n < 4; ++n) {
      s0[n] = (f4){-64.f, -64.f, -64.f, -64.f};
      s1[n] = (f4){-64.f, -64.f, -64.f, -64.f};
    }
    __builtin_amdgcn_s_setprio(1);
#pragma unroll
    for (int n = 0; n < 4; ++n) {
      const int row = n * 16 + qlo;
      const int swz = (row & 7) ^ (row >> 3);
#pragma unroll
      for (int kk = 0; kk < 2; ++kk) {
        const s8b kf = *(const s8b*)(&Kl[row * 64 + ((((kk << 2) + hi) ^ swz) << 3)]);
        s0[n] = __builtin_amdgcn_mfma_f32_16x16x32_bf16(kf, qf[0][kk], s0[n], 0, 0, 0);
        s1[n] = __builtin_amdgcn_mfma_f32_16x16x32_bf16(kf, qf[1][kk], s1[n], 0, 0, 0);
      }
    }
    __builtin_amdgcn_s_setprio(0);

    const int dmb = (2 * qi - kt) * 64;
    if (dmb < 64) {
      const int thr0 = w * 32 + qlo + dmb;
      const int thr1 = thr0 + 16;
#pragma unroll
      for (int n = 0; n < 4; ++n)
#pragma unroll
        for (int j = 0; j < 4; ++j) {
          const int kidx = n * 16 + hi * 4 + j;
          if (kidx > thr0) s0[n][j] = -1e30f;
          if (kidx > thr1) s1[n][j] = -1e30f;
        }
    }

    U8 pf0[2], pf1[2];
    softpack(s0, pf0);
    softpack(s1, pf1);

    __builtin_amdgcn_s_setprio(1);
#pragma unroll
    for (int dn = 0; dn < 4; ++dn) {
      const int vrow = dn * 16 + qlo;
      const int vswz = (vrow & 7) ^ (vrow >> 3);
#pragma unroll
      for (int kk = 0; kk < 2; ++kk) {
        const s8b vf = *(const s8b*)(&VTl[vrow * 64 + ((((kk << 2) + hi) ^ vswz) << 3)]);
        acc0[dn] = __builtin_amdgcn_mfma_f32_16x16x32_bf16(pf0[kk].v, vf, acc0[dn], 0, 0, 0);
        acc1[dn] = __builtin_amdgcn_mfma_f32_16x16x32_bf16(pf1[kk].v, vf, acc1[dn], 0, 0, 0);
      }
    }
#pragma unroll
    for (int kk = 0; kk < 2; ++kk) {
      acc0[4] = __builtin_amdgcn_mfma_f32_16x16x32_bf16(pf0[kk].v, ones, acc0[4], 0, 0, 0);
      acc1[4] = __builtin_amdgcn_mfma_f32_16x16x32_bf16(pf1[kk].v, ones, acc1[4], 0, 0, 0);
    }
    __builtin_amdgcn_s_setprio(0);

    __syncthreads();
    if (pf_next) {
      write_lds();
      __syncthreads();
    }
  }

#pragma unroll
  for (int g = 0; g < 2; ++g) {
    const f4* accg = g ? acc1 : acc0;
#pragma unroll
    for (int j = 0; j < 4; ++j) {
      const float rl = 1.0f / accg[4][j];
      const int t = qi * 128 + w * 32 + g * 16 + hi * 4 + j;
#pragma unroll
      for (int dn = 0; dn < 4; ++dn) {
        const int dcol = dn * 16 + qlo;
        ao[((size_t)(b * 2048 + t)) * 1024 + h16 * 64 + dcol] = f2bf(accg[dn][j] * rl);
      }
    }
  }
}

extern "C" void kernel_launch(void* const* d_in, const int* in_sizes, int n_in,
                              void* d_out, int out_size, void* d_ws, size_t ws_size,
                              hipStream_t stream) {
  const float* x = (const float*)d_in[0];
  const float* w_attn = (const float*)d_in[1];
  const float* w_proj = (const float*)d_in[2];
  float* out = (float*)d_out;
  char* ws = (char*)d_ws;

  u16* xb  = (u16*)(ws);
  u16* wab = (u16*)(ws + (16u << 20));
  u16* wpb = (u16*)(ws + (22u << 20));
  u16* qb  = (u16*)(ws + (24u << 20));
  u16* kb  = (u16*)(ws + (40u << 20));
  u16* vb  = (u16*)(ws + (56u << 20));   // V^T [B,H,D,T]
  u16* ao  = xb;  // alias: xb dead after GEMM1

  cvt3_kernel<<<6144, 256, 0, stream>>>(x, w_attn, w_proj, xb, wab, wpb);

  // GEMM1: M=8192, N=3072, K=1024 -> 1536 blocks, single-buffer m97 structure
  gemm_sb<0><<<1536, 256, 0, stream>>>(xb, wab, nullptr, qb, kb, vb,
                                       3072, 1024);
  // attn: 1024 blocks, 24KB LDS single-buffer -> 4 blocks/CU resident
  attn_kernel<<<1024, 256, 0, stream>>>(qb, kb, vb, ao);
  // GEMM2: M=8192, N=1024, K=1024 -> 512 blocks x 1 tile (double-buffered)
  gemm_bt<1, 1><<<512, 256, 0, stream>>>(ao, wpb, out, nullptr, nullptr, nullptr,
                                         1024, 1024, 8);
}